// Round 13
// baseline (131.196 us; speedup 1.0000x reference)
//
#include <hip/hip_runtime.h>

// Dims fixed by setup_inputs: B=2, S=2048, D=1024, F=4096, T=8
#define N_ROWS 4096
#define DDIM   1024
#define FDIM   4096

typedef unsigned short u16;
typedef __attribute__((ext_vector_type(8))) _Float16 f16x8;
typedef __attribute__((ext_vector_type(4))) float f32x4;

#define MFMA16(a, b, c) __builtin_amdgcn_mfma_f32_16x16x32_f16((a), (b), (c), 0, 0, 0)

static __device__ __forceinline__ u16 f2h_bits(float f) {
    _Float16 h = (_Float16)f;
    return __builtin_bit_cast(u16, h);
}
static __device__ __forceinline__ void gload_lds16(const u16* g, u16* l) {
    __builtin_amdgcn_global_load_lds((const __attribute__((address_space(1))) unsigned*)g,
                                     (__attribute__((address_space(3))) unsigned*)l, 16, 0, 0);
}

// ---- fused prepass: x -> xh fp16 ; wup -> wh ; wdown -> wd ; zero colsum ----
__global__ __launch_bounds__(256) void split_all(
    const float* __restrict__ x, const float* __restrict__ wup,
    const float* __restrict__ wdown,
    u16* __restrict__ xh, u16* __restrict__ wh, u16* __restrict__ wd,
    float* __restrict__ colsum)
{
    const int N4 = (N_ROWS * DDIM) / 4;   // 2^20 float4 per array
    int i = blockIdx.x * 256 + threadIdx.x;
    if (i < FDIM / 4) ((float4*)colsum)[i] = (float4){0.f, 0.f, 0.f, 0.f};
    const int stride = gridDim.x * 256;
    for (; i < 3 * N4; i += stride) {
        const int r = i >> 20;
        const int j = i & (N4 - 1);
        const float4 v = (r == 0) ? ((const float4*)x)[j]
                       : (r == 1) ? ((const float4*)wup)[j]
                                  : ((const float4*)wdown)[j];
        ushort4 h;
        h.x = f2h_bits(v.x); h.y = f2h_bits(v.y);
        h.z = f2h_bits(v.z); h.w = f2h_bits(v.w);
        if (r == 0)      ((ushort4*)xh)[j] = h;
        else if (r == 1) ((ushort4*)wh)[j] = h;
        else             ((ushort4*)wd)[j] = h;
    }
}

// ---- up-GEMM: 128x256 tile, BK=32, 256 threads / 4 waves (2Mx2N,
//      wave-tile 64x128), fp16 single product, 3-slot counted-vmcnt rotation
//      (6 gloads/tile, vmcnt(6), never 0 mid-loop), 0-conflict XOR LDS.
//      72KB LDS -> 2 independent blocks/CU (bubble fill + epilogue overlap).
//      Fused LIF + column-sum epilogue. ----
__global__ __launch_bounds__(256, 2) void up_mfma(
    const u16* __restrict__ xh, const u16* __restrict__ wh,
    const float* __restrict__ beta, const int* __restrict__ Tp,
    u16* __restrict__ rate, float* __restrict__ colsum)
{
    // slot = A[128][32] (8KB) + B[256][32] (16KB) = 24KB; 3 slots = 72KB
    __shared__ __align__(16) u16 lds[3 * 12288];

    const int t = threadIdx.x;
    const int l = t & 63, w = t >> 6;          // 4 waves
    const int wm = w >> 1, wn = w & 1;         // wave-tile 64(M) x 128(N)

    // per-XCD 8bm x 8bn rectangle (grid 32bm x 16bn = 512 blocks)
    const int flat = blockIdx.y * gridDim.x + blockIdx.x;   // 0..511
    const int xcd = flat & 7, wi = flat >> 3;               // wi 0..63
    const int bm = ((xcd & 3) * 8 + (wi & 7)) * 128;
    const int bn = ((xcd >> 2) * 8 + (wi >> 3)) * 256;

    // staging: each gload issue = 4KB page (64 rows x 64B); dest linear t*16B;
    // source k pre-swizzled (involution with read-side XOR, key=(row>>1)&3)
    const int koff = (((t & 3) ^ ((t >> 3) & 3)) << 3);
    const int srow = t >> 2;                   // 0..63
    const size_t gA0 = (size_t)(bm + srow) * DDIM + koff;
    const size_t gA1 = gA0 + (size_t)64 * DDIM;
    const size_t gB0 = (size_t)(bn + srow) * DDIM + koff;
    const int dst = t * 8;

#define STG(slot, step) do {                                                  \
    const size_t k0_ = (size_t)(step) << 5;                                   \
    u16* Lb_ = &lds[(slot) * 12288];                                          \
    gload_lds16(xh + gA0 + k0_, Lb_ + dst);                                   \
    gload_lds16(xh + gA1 + k0_, Lb_ + 2048 + dst);                            \
    gload_lds16(wh + gB0 + k0_, Lb_ + 4096 + dst);                            \
    gload_lds16(wh + gB0 + (size_t)64 * DDIM + k0_, Lb_ + 6144 + dst);        \
    gload_lds16(wh + gB0 + (size_t)128 * DDIM + k0_, Lb_ + 8192 + dst);       \
    gload_lds16(wh + gB0 + (size_t)192 * DDIM + k0_, Lb_ + 10240 + dst);      \
} while (0)

    // fragment reads (0-conflict XOR; page = row>>6, key invariant under +16s)
    const int lr = l & 15, lk = l >> 4;
    const int psl = ((lk ^ ((lr >> 1) & 3)) << 3);

    f32x4 acc[4][8];
#pragma unroll
    for (int m = 0; m < 4; ++m)
#pragma unroll
        for (int n = 0; n < 8; ++n) acc[m][n] = (f32x4){0.f, 0.f, 0.f, 0.f};

    // prologue: stage tiles 0,1 (12 loads in flight)
    STG(0, 0);
    STG(1, 1);

    const int NT = DDIM / 32;   // 32
#pragma unroll 1
    for (int ts = 0; ts < NT; ++ts) {
        // counted wait: tile ts's 6 loads landed (<=6 newest may pend)
        if (ts + 1 < NT) { asm volatile("s_waitcnt vmcnt(6)" ::: "memory"); }
        else             { asm volatile("s_waitcnt vmcnt(0)" ::: "memory"); }
        __builtin_amdgcn_s_barrier();

        // stage tile ts+2 into the slot last read at ts-1 (race-free via the
        // barrier above: all waves' ts-1 reads precede their ts barrier)
        if (ts + 2 < NT) STG((ts + 2) % 3, ts + 2);

        const int sb = (ts % 3) * 12288;
        f16x8 a[4], b[8];
#pragma unroll
        for (int m = 0; m < 4; ++m) {
            const int rowin = wm * 64 + m * 16 + lr;   // 0..127
            a[m] = *(const f16x8*)&lds[sb + (rowin >> 6) * 2048 + (rowin & 63) * 32 + psl];
        }
#pragma unroll
        for (int n = 0; n < 8; ++n) {
            const int rowin = wn * 128 + n * 16 + lr;  // 0..255
            b[n] = *(const f16x8*)&lds[sb + 4096 + (rowin >> 6) * 2048 + (rowin & 63) * 32 + psl];
        }
        __builtin_amdgcn_s_setprio(1);
#pragma unroll
        for (int m = 0; m < 4; ++m)
#pragma unroll
            for (int n = 0; n < 8; ++n)
                acc[m][n] = MFMA16(a[m], b[n], acc[m][n]);
        __builtin_amdgcn_s_setprio(0);
    }
#undef STG

    // ---- epilogue: LIF recurrence, rate write, fused column sums ----
    const int T = Tp[0];
    const float invT = 1.0f / (float)T;
    const int fbase = bn + wn * 128;
    float betav[8], colacc[8];
#pragma unroll
    for (int n = 0; n < 8; ++n) { betav[n] = beta[fbase + n * 16 + lr]; colacc[n] = 0.f; }

#pragma unroll
    for (int m = 0; m < 4; ++m) {
#pragma unroll
        for (int r = 0; r < 4; ++r) {
            const int row = bm + wm * 64 + m * 16 + lk * 4 + r;
            u16* rp = rate + (size_t)row * FDIM + fbase + lr;
#pragma unroll
            for (int n = 0; n < 8; ++n) {
                const float h = acc[m][n][r];
                const float bet = betav[n];
                float v = 0.f, ss = 0.f;
                if (T == 8) {
#pragma unroll
                    for (int tt = 0; tt < 8; ++tt) {
                        v = fmaf(bet, v, h);
                        float s = (v > 1.0f) ? 1.0f : 0.0f;
                        ss += s; v -= s;
                    }
                } else {
                    for (int tt = 0; tt < T; ++tt) {
                        v = fmaf(bet, v, h);
                        float s = (v > 1.0f) ? 1.0f : 0.0f;
                        ss += s; v -= s;
                    }
                }
                const float rv = ss * invT;                 // exact k/8 (fp16-exact)
                rp[n * 16] = f2h_bits(rv);
                colacc[n] += rv;
            }
        }
    }
#pragma unroll
    for (int n = 0; n < 8; ++n) {
        float ca = colacc[n];
        ca += __shfl_xor(ca, 16, 64);
        ca += __shfl_xor(ca, 32, 64);
        if (lk == 0) atomicAdd(&colsum[fbase + n * 16 + lr], ca);  // exact eighths
    }
}

// ---- down-GEMM: 128x128 tile, BK=64, 8 waves (2Mx4N, wave-tile 64x32),
//      fp16 16x16x32 MFMA, 3-slot counted-vmcnt rotation, 0-conflict XOR LDS.
//      out = rate(fp16) @ wd(fp16)^T, fp32 out. (R8-proven, unchanged) ----
__global__ __launch_bounds__(512, 1) void down_mfma(
    const u16* __restrict__ rate, const u16* __restrict__ wd,
    float* __restrict__ out)
{
    __shared__ __align__(16) u16 lds[3 * 16384];

    const int t = threadIdx.x;
    const int l = t & 63, w = t >> 6;
    const int wm = w >> 2, wn = w & 3;          // wave tile 64x32

    const int flat = blockIdx.y * gridDim.x + blockIdx.x;   // 0..255
    const int xcd = flat & 7, wi = flat >> 3;               // wi 0..31
    const int bm = ((xcd & 3) * 8 + (wi & 7)) * 128;
    const int bn = ((xcd >> 2) * 4 + (wi >> 3)) * 128;

    const int srow = t >> 3;                                // 0..63
    const int koff = (((t & 7) ^ ((t >> 3) & 7)) << 3);
    const size_t gA0 = (size_t)(bm + srow) * FDIM + koff;
    const size_t gA1 = gA0 + (size_t)64 * FDIM;
    const size_t gB0 = (size_t)(bn + srow) * FDIM + koff;
    const size_t gB1 = gB0 + (size_t)64 * FDIM;
    const int dst = t * 8;

#define STD(slot, step) do {                                                  \
    const size_t k0_ = (size_t)(step) << 6;                                   \
    u16* Lb_ = &lds[(slot) * 16384];                                          \
    gload_lds16(rate + gA0 + k0_, Lb_ + dst);                                 \
    gload_lds16(rate + gA1 + k0_, Lb_ + 4096 + dst);                          \
    gload_lds16(wd + gB0 + k0_, Lb_ + 8192 + dst);                            \
    gload_lds16(wd + gB1 + k0_, Lb_ + 12288 + dst);                           \
} while (0)

    const int lr = l & 15, lk = l >> 4;
    const int key = lr & 7;
    const int ps0 = ((0 * 4 + lk) ^ key) << 3;
    const int ps1 = ((1 * 4 + lk) ^ key) << 3;

    f32x4 acc[4][2];
#pragma unroll
    for (int m = 0; m < 4; ++m) {
        acc[m][0] = (f32x4){0.f, 0.f, 0.f, 0.f};
        acc[m][1] = (f32x4){0.f, 0.f, 0.f, 0.f};
    }

    STD(0, 0);
    STD(1, 1);

    const int NT = FDIM / 64;   // 64
#pragma unroll 1
    for (int ts = 0; ts < NT; ++ts) {
        if (ts + 1 < NT) { asm volatile("s_waitcnt vmcnt(4)" ::: "memory"); }
        else             { asm volatile("s_waitcnt vmcnt(0)" ::: "memory"); }
        __builtin_amdgcn_s_barrier();

        if (ts + 2 < NT) STD((ts + 2) % 3, ts + 2);

        const int sb = (ts % 3) * 16384;
        f16x8 a[4][2], b[2][2];
#pragma unroll
        for (int m = 0; m < 4; ++m) {
            const int ro = sb + (wm * 64 + m * 16 + lr) * 64;
            a[m][0] = *(const f16x8*)&lds[ro + ps0];
            a[m][1] = *(const f16x8*)&lds[ro + ps1];
        }
#pragma unroll
        for (int n = 0; n < 2; ++n) {
            const int ro = sb + 8192 + (wn * 32 + n * 16 + lr) * 64;
            b[n][0] = *(const f16x8*)&lds[ro + ps0];
            b[n][1] = *(const f16x8*)&lds[ro + ps1];
        }
        __builtin_amdgcn_s_setprio(1);
#pragma unroll
        for (int m = 0; m < 4; ++m)
#pragma unroll
            for (int n = 0; n < 2; ++n) {
                f32x4 c = acc[m][n];
                c = MFMA16(a[m][0], b[n][0], c);
                c = MFMA16(a[m][1], b[n][1], c);
                acc[m][n] = c;
            }
        __builtin_amdgcn_s_setprio(0);
    }
#undef STD

#pragma unroll
    for (int n = 0; n < 2; ++n) {
        const int d = bn + wn * 32 + n * 16 + lr;
#pragma unroll
        for (int m = 0; m < 4; ++m) {
            const int row0 = bm + wm * 64 + m * 16 + lk * 4;
#pragma unroll
            for (int r = 0; r < 4; ++r)
                out[(size_t)(row0 + r) * DDIM + d] = acc[m][n][r];
        }
    }
}

// ---- rate_per_unit ----
__global__ void finalize_rpu(const float* __restrict__ colsum, float* __restrict__ out_rpu) {
    const int f = blockIdx.x * 256 + threadIdx.x;
    out_rpu[f] = colsum[f] * (1.0f / (float)N_ROWS);
}

extern "C" void kernel_launch(void* const* d_in, const int* in_sizes, int n_in,
                              void* d_out, int out_size, void* d_ws, size_t ws_size,
                              hipStream_t stream) {
    const float* x     = (const float*)d_in[0];
    const float* wup   = (const float*)d_in[1];
    const float* wdown = (const float*)d_in[2];
    const float* beta  = (const float*)d_in[3];
    const int*   Tp    = (const int*)d_in[4];

    float* out     = (float*)d_out;
    float* out_rpu = out + (size_t)N_ROWS * DDIM;

    char* ws = (char*)d_ws;
    u16* rate = (u16*)ws;                                   // 33,554,432 B
    u16* xh   = (u16*)(ws + 33554432);
    u16* wh   = (u16*)(ws + 33554432 + 8388608);
    u16* wd   = (u16*)(ws + 33554432 + 2 * 8388608);
    float* colsum = (float*)(ws + 33554432 + 3 * 8388608);

    split_all<<<2048, 256, 0, stream>>>(x, wup, wdown, xh, wh, wd, colsum);

    up_mfma<<<dim3(16, 32), 256, 0, stream>>>(xh, wh, beta, Tp, rate, colsum);

    finalize_rpu<<<FDIM / 256, 256, 0, stream>>>(colsum, out_rpu);

    down_mfma<<<dim3(DDIM / 128, N_ROWS / 128), 512, 0, stream>>>(rate, wd, out);
}

// Round 14
// 129.686 us; speedup vs baseline: 1.0116x; 1.0116x over previous
//
#include <hip/hip_runtime.h>

// Dims fixed by setup_inputs: B=2, S=2048, D=1024, F=4096, T=8
#define N_ROWS 4096
#define DDIM   1024
#define FDIM   4096

typedef unsigned short u16;
typedef __attribute__((ext_vector_type(8))) _Float16 f16x8;
typedef __attribute__((ext_vector_type(4))) float f32x4;

#define MFMA16(a, b, c) __builtin_amdgcn_mfma_f32_16x16x32_f16((a), (b), (c), 0, 0, 0)

static __device__ __forceinline__ u16 f2h_bits(float f) {
    _Float16 h = (_Float16)f;
    return __builtin_bit_cast(u16, h);
}
static __device__ __forceinline__ void gload_lds16(const u16* g, u16* l) {
    __builtin_amdgcn_global_load_lds((const __attribute__((address_space(1))) unsigned*)g,
                                     (__attribute__((address_space(3))) unsigned*)l, 16, 0, 0);
}

// ---- fused prepass: x -> xh fp16 ; wup -> wh ; wdown -> wd ; zero colsum ----
__global__ __launch_bounds__(256) void split_all(
    const float* __restrict__ x, const float* __restrict__ wup,
    const float* __restrict__ wdown,
    u16* __restrict__ xh, u16* __restrict__ wh, u16* __restrict__ wd,
    float* __restrict__ colsum)
{
    const int N4 = (N_ROWS * DDIM) / 4;   // 2^20 float4 per array
    int i = blockIdx.x * 256 + threadIdx.x;
    if (i < FDIM / 4) ((float4*)colsum)[i] = (float4){0.f, 0.f, 0.f, 0.f};
    const int stride = gridDim.x * 256;
    for (; i < 3 * N4; i += stride) {
        const int r = i >> 20;
        const int j = i & (N4 - 1);
        const float4 v = (r == 0) ? ((const float4*)x)[j]
                       : (r == 1) ? ((const float4*)wup)[j]
                                  : ((const float4*)wdown)[j];
        ushort4 h;
        h.x = f2h_bits(v.x); h.y = f2h_bits(v.y);
        h.z = f2h_bits(v.z); h.w = f2h_bits(v.w);
        if (r == 0)      ((ushort4*)xh)[j] = h;
        else if (r == 1) ((ushort4*)wh)[j] = h;
        else             ((ushort4*)wd)[j] = h;
    }
}

// ---- up-GEMM: 128x256 tile, BK=64, 512 threads / 8 waves (2Mx4N,
//      wave-tile 64x64), fp16 single product, 3-slot counted-vmcnt rotation
//      (6 gloads/tile, vmcnt(6), never 0 mid-loop), down-proven 128B-row
//      XOR LDS layout (key=row&7, 0 conflicts). 16 K-steps (2x fewer than
//      BK=32 -> per-step overhead amortized). Fused LIF + colsum epilogue. ----
__global__ __launch_bounds__(512, 1) void up_mfma(
    const u16* __restrict__ xh, const u16* __restrict__ wh,
    const float* __restrict__ beta, const int* __restrict__ Tp,
    u16* __restrict__ rate, float* __restrict__ colsum)
{
    // slot = A[128][64] (16KB) + B[256][64] (32KB) = 48KB; 3 slots = 144KB
    __shared__ __align__(16) u16 lds[3 * 24576];

    const int t = threadIdx.x;
    const int l = t & 63, w = t >> 6;
    const int wm = w >> 2, wn = w & 3;          // wave-tile 64(M) x 64(N)

    // per-XCD 8bm x 8bn rectangle (grid 32bm x 16bn = 512 blocks)
    const int flat = blockIdx.y * gridDim.x + blockIdx.x;   // 0..511
    const int xcd = flat & 7, wi = flat >> 3;               // wi 0..63
    const int bm = ((xcd & 3) * 8 + (wi & 7)) * 128;
    const int bn = ((xcd >> 2) * 8 + (wi >> 3)) * 256;

    // staging: issue = 8KB page (64 rows x 128B); dest linear t*16B;
    // source k pre-swizzled (involution w/ read XOR, key = row&7)
    const int srow = t >> 3;                                // 0..63
    const int koff = (((t & 7) ^ ((t >> 3) & 7)) << 3);
    const size_t gA0 = (size_t)(bm + srow) * DDIM + koff;
    const size_t gA1 = gA0 + (size_t)64 * DDIM;
    const size_t gB0 = (size_t)(bn + srow) * DDIM + koff;
    const int dst = t * 8;

#define STG(slot, step) do {                                                  \
    const size_t k0_ = (size_t)(step) << 6;                                   \
    u16* Lb_ = &lds[(slot) * 24576];                                          \
    gload_lds16(xh + gA0 + k0_, Lb_ + dst);                                   \
    gload_lds16(xh + gA1 + k0_, Lb_ + 4096 + dst);                            \
    gload_lds16(wh + gB0 + k0_, Lb_ + 8192 + dst);                            \
    gload_lds16(wh + gB0 + (size_t)64 * DDIM + k0_, Lb_ + 12288 + dst);       \
    gload_lds16(wh + gB0 + (size_t)128 * DDIM + k0_, Lb_ + 16384 + dst);      \
    gload_lds16(wh + gB0 + (size_t)192 * DDIM + k0_, Lb_ + 20480 + dst);      \
} while (0)

    // fragment reads (down-proven: logical slot L = g*4+lk, phys = L^(row&7))
    const int lr = l & 15, lk = l >> 4;
    const int key = lr & 7;
    const int ps0 = ((0 * 4 + lk) ^ key) << 3;
    const int ps1 = ((1 * 4 + lk) ^ key) << 3;

    f32x4 acc[4][4];
#pragma unroll
    for (int m = 0; m < 4; ++m)
#pragma unroll
        for (int n = 0; n < 4; ++n) acc[m][n] = (f32x4){0.f, 0.f, 0.f, 0.f};

    // prologue: stage tiles 0,1 (12 loads in flight)
    STG(0, 0);
    STG(1, 1);

    const int NT = DDIM / 64;   // 16
#pragma unroll 1
    for (int ts = 0; ts < NT; ++ts) {
        // counted wait: tile ts's 6 loads landed (<=6 newest may pend)
        if (ts + 1 < NT) { asm volatile("s_waitcnt vmcnt(6)" ::: "memory"); }
        else             { asm volatile("s_waitcnt vmcnt(0)" ::: "memory"); }
        __builtin_amdgcn_s_barrier();

        // stage tile ts+2 into the slot last read at ts-1 (race-free)
        if (ts + 2 < NT) STG((ts + 2) % 3, ts + 2);

        const int sb = (ts % 3) * 24576;
        f16x8 a[4][2], b[4][2];
#pragma unroll
        for (int m = 0; m < 4; ++m) {
            const int ro = sb + (wm * 64 + m * 16 + lr) * 64;
            a[m][0] = *(const f16x8*)&lds[ro + ps0];
            a[m][1] = *(const f16x8*)&lds[ro + ps1];
        }
#pragma unroll
        for (int n = 0; n < 4; ++n) {
            const int ro = sb + 8192 + (wn * 64 + n * 16 + lr) * 64;
            b[n][0] = *(const f16x8*)&lds[ro + ps0];
            b[n][1] = *(const f16x8*)&lds[ro + ps1];
        }
        __builtin_amdgcn_s_setprio(1);
#pragma unroll
        for (int m = 0; m < 4; ++m)
#pragma unroll
            for (int n = 0; n < 4; ++n) {
                f32x4 c = acc[m][n];
                c = MFMA16(a[m][0], b[n][0], c);
                c = MFMA16(a[m][1], b[n][1], c);
                acc[m][n] = c;
            }
        __builtin_amdgcn_s_setprio(0);
    }
#undef STG

    // ---- epilogue: LIF recurrence, rate write, fused column sums ----
    const int T = Tp[0];
    const float invT = 1.0f / (float)T;
    const int fbase = bn + wn * 64;
    float betav[4], colacc[4];
#pragma unroll
    for (int n = 0; n < 4; ++n) { betav[n] = beta[fbase + n * 16 + lr]; colacc[n] = 0.f; }

#pragma unroll
    for (int m = 0; m < 4; ++m) {
#pragma unroll
        for (int r = 0; r < 4; ++r) {
            const int row = bm + wm * 64 + m * 16 + lk * 4 + r;
            u16* rp = rate + (size_t)row * FDIM + fbase + lr;
#pragma unroll
            for (int n = 0; n < 4; ++n) {
                const float h = acc[m][n][r];
                const float bet = betav[n];
                float v = 0.f, ss = 0.f;
                if (T == 8) {
#pragma unroll
                    for (int tt = 0; tt < 8; ++tt) {
                        v = fmaf(bet, v, h);
                        float s = (v > 1.0f) ? 1.0f : 0.0f;
                        ss += s; v -= s;
                    }
                } else {
                    for (int tt = 0; tt < T; ++tt) {
                        v = fmaf(bet, v, h);
                        float s = (v > 1.0f) ? 1.0f : 0.0f;
                        ss += s; v -= s;
                    }
                }
                const float rv = ss * invT;                 // exact k/8 (fp16-exact)
                rp[n * 16] = f2h_bits(rv);
                colacc[n] += rv;
            }
        }
    }
#pragma unroll
    for (int n = 0; n < 4; ++n) {
        float ca = colacc[n];
        ca += __shfl_xor(ca, 16, 64);
        ca += __shfl_xor(ca, 32, 64);
        if (lk == 0) atomicAdd(&colsum[fbase + n * 16 + lr], ca);  // exact eighths
    }
}

// ---- down-GEMM: 128x128 tile, BK=64, 8 waves (2Mx4N, wave-tile 64x32),
//      fp16 16x16x32 MFMA, 3-slot counted-vmcnt rotation, 0-conflict XOR LDS.
//      out = rate(fp16) @ wd(fp16)^T, fp32 out. (R8-proven, unchanged) ----
__global__ __launch_bounds__(512, 1) void down_mfma(
    const u16* __restrict__ rate, const u16* __restrict__ wd,
    float* __restrict__ out)
{
    __shared__ __align__(16) u16 lds[3 * 16384];

    const int t = threadIdx.x;
    const int l = t & 63, w = t >> 6;
    const int wm = w >> 2, wn = w & 3;          // wave tile 64x32

    const int flat = blockIdx.y * gridDim.x + blockIdx.x;   // 0..255
    const int xcd = flat & 7, wi = flat >> 3;               // wi 0..31
    const int bm = ((xcd & 3) * 8 + (wi & 7)) * 128;
    const int bn = ((xcd >> 2) * 4 + (wi >> 3)) * 128;

    const int srow = t >> 3;                                // 0..63
    const int koff = (((t & 7) ^ ((t >> 3) & 7)) << 3);
    const size_t gA0 = (size_t)(bm + srow) * FDIM + koff;
    const size_t gA1 = gA0 + (size_t)64 * FDIM;
    const size_t gB0 = (size_t)(bn + srow) * FDIM + koff;
    const size_t gB1 = gB0 + (size_t)64 * FDIM;
    const int dst = t * 8;

#define STD(slot, step) do {                                                  \
    const size_t k0_ = (size_t)(step) << 6;                                   \
    u16* Lb_ = &lds[(slot) * 16384];                                          \
    gload_lds16(rate + gA0 + k0_, Lb_ + dst);                                 \
    gload_lds16(rate + gA1 + k0_, Lb_ + 4096 + dst);                          \
    gload_lds16(wd + gB0 + k0_, Lb_ + 8192 + dst);                            \
    gload_lds16(wd + gB1 + k0_, Lb_ + 12288 + dst);                           \
} while (0)

    const int lr = l & 15, lk = l >> 4;
    const int key = lr & 7;
    const int ps0 = ((0 * 4 + lk) ^ key) << 3;
    const int ps1 = ((1 * 4 + lk) ^ key) << 3;

    f32x4 acc[4][2];
#pragma unroll
    for (int m = 0; m < 4; ++m) {
        acc[m][0] = (f32x4){0.f, 0.f, 0.f, 0.f};
        acc[m][1] = (f32x4){0.f, 0.f, 0.f, 0.f};
    }

    STD(0, 0);
    STD(1, 1);

    const int NT = FDIM / 64;   // 64
#pragma unroll 1
    for (int ts = 0; ts < NT; ++ts) {
        if (ts + 1 < NT) { asm volatile("s_waitcnt vmcnt(4)" ::: "memory"); }
        else             { asm volatile("s_waitcnt vmcnt(0)" ::: "memory"); }
        __builtin_amdgcn_s_barrier();

        if (ts + 2 < NT) STD((ts + 2) % 3, ts + 2);

        const int sb = (ts % 3) * 16384;
        f16x8 a[4][2], b[2][2];
#pragma unroll
        for (int m = 0; m < 4; ++m) {
            const int ro = sb + (wm * 64 + m * 16 + lr) * 64;
            a[m][0] = *(const f16x8*)&lds[ro + ps0];
            a[m][1] = *(const f16x8*)&lds[ro + ps1];
        }
#pragma unroll
        for (int n = 0; n < 2; ++n) {
            const int ro = sb + 8192 + (wn * 32 + n * 16 + lr) * 64;
            b[n][0] = *(const f16x8*)&lds[ro + ps0];
            b[n][1] = *(const f16x8*)&lds[ro + ps1];
        }
        __builtin_amdgcn_s_setprio(1);
#pragma unroll
        for (int m = 0; m < 4; ++m)
#pragma unroll
            for (int n = 0; n < 2; ++n) {
                f32x4 c = acc[m][n];
                c = MFMA16(a[m][0], b[n][0], c);
                c = MFMA16(a[m][1], b[n][1], c);
                acc[m][n] = c;
            }
        __builtin_amdgcn_s_setprio(0);
    }
#undef STD

#pragma unroll
    for (int n = 0; n < 2; ++n) {
        const int d = bn + wn * 32 + n * 16 + lr;
#pragma unroll
        for (int m = 0; m < 4; ++m) {
            const int row0 = bm + wm * 64 + m * 16 + lk * 4;
#pragma unroll
            for (int r = 0; r < 4; ++r)
                out[(size_t)(row0 + r) * DDIM + d] = acc[m][n][r];
        }
    }
}

// ---- rate_per_unit ----
__global__ void finalize_rpu(const float* __restrict__ colsum, float* __restrict__ out_rpu) {
    const int f = blockIdx.x * 256 + threadIdx.x;
    out_rpu[f] = colsum[f] * (1.0f / (float)N_ROWS);
}

extern "C" void kernel_launch(void* const* d_in, const int* in_sizes, int n_in,
                              void* d_out, int out_size, void* d_ws, size_t ws_size,
                              hipStream_t stream) {
    const float* x     = (const float*)d_in[0];
    const float* wup   = (const float*)d_in[1];
    const float* wdown = (const float*)d_in[2];
    const float* beta  = (const float*)d_in[3];
    const int*   Tp    = (const int*)d_in[4];

    float* out     = (float*)d_out;
    float* out_rpu = out + (size_t)N_ROWS * DDIM;

    char* ws = (char*)d_ws;
    u16* rate = (u16*)ws;                                   // 33,554,432 B
    u16* xh   = (u16*)(ws + 33554432);
    u16* wh   = (u16*)(ws + 33554432 + 8388608);
    u16* wd   = (u16*)(ws + 33554432 + 2 * 8388608);
    float* colsum = (float*)(ws + 33554432 + 3 * 8388608);

    split_all<<<2048, 256, 0, stream>>>(x, wup, wdown, xh, wh, wd, colsum);

    up_mfma<<<dim3(16, 32), 512, 0, stream>>>(xh, wh, beta, Tp, rate, colsum);

    finalize_rpu<<<FDIM / 256, 256, 0, stream>>>(colsum, out_rpu);

    down_mfma<<<dim3(DDIM / 128, N_ROWS / 128), 512, 0, stream>>>(rate, wd, out);
}

// Round 15
// 120.648 us; speedup vs baseline: 1.0874x; 1.0749x over previous
//
#include <hip/hip_runtime.h>

// Dims fixed by setup_inputs: B=2, S=2048, D=1024, F=4096, T=8
#define N_ROWS 4096
#define DDIM   1024
#define FDIM   4096

typedef unsigned short u16;
typedef __attribute__((ext_vector_type(8))) _Float16 f16x8;
typedef __attribute__((ext_vector_type(4))) float f32x4;

#define MFMA16(a, b, c) __builtin_amdgcn_mfma_f32_16x16x32_f16((a), (b), (c), 0, 0, 0)

static __device__ __forceinline__ u16 f2h_bits(float f) {
    _Float16 h = (_Float16)f;
    return __builtin_bit_cast(u16, h);
}
static __device__ __forceinline__ void gload_lds16(const u16* g, u16* l) {
    __builtin_amdgcn_global_load_lds((const __attribute__((address_space(1))) unsigned*)g,
                                     (__attribute__((address_space(3))) unsigned*)l, 16, 0, 0);
}

// ---- fused prepass: x -> xh fp16 ; wup -> wh ; wdown -> wd ; zero colsum ----
__global__ __launch_bounds__(256) void split_all(
    const float* __restrict__ x, const float* __restrict__ wup,
    const float* __restrict__ wdown,
    u16* __restrict__ xh, u16* __restrict__ wh, u16* __restrict__ wd,
    float* __restrict__ colsum)
{
    const int N4 = (N_ROWS * DDIM) / 4;   // 2^20 float4 per array
    int i = blockIdx.x * 256 + threadIdx.x;
    if (i < FDIM / 4) ((float4*)colsum)[i] = (float4){0.f, 0.f, 0.f, 0.f};
    const int stride = gridDim.x * 256;
    for (; i < 3 * N4; i += stride) {
        const int r = i >> 20;
        const int j = i & (N4 - 1);
        const float4 v = (r == 0) ? ((const float4*)x)[j]
                       : (r == 1) ? ((const float4*)wup)[j]
                                  : ((const float4*)wdown)[j];
        ushort4 h;
        h.x = f2h_bits(v.x); h.y = f2h_bits(v.y);
        h.z = f2h_bits(v.z); h.w = f2h_bits(v.w);
        if (r == 0)      ((ushort4*)xh)[j] = h;
        else if (r == 1) ((ushort4*)wh)[j] = h;
        else             ((ushort4*)wd)[j] = h;
    }
}

// ---- up-GEMM: 128x128 tile, BK=32, 8 waves (4Mx2N, wave-tile 32x64),
//      fp16 single product, SMALL footprint: acc[2][4]=32 AGPR, 48KB LDS
//      -> 2-3 independent blocks/CU, 4-6 waves/SIMD (bubble-filling).
//      3-slot counted-vmcnt rotation (2 gloads/tile, vmcnt(2), never 0
//      mid-loop), R12-proven XOR swizzle. Fused LIF + colsum epilogue. ----
__global__ __launch_bounds__(512, 4) void up_mfma(
    const u16* __restrict__ xh, const u16* __restrict__ wh,
    const float* __restrict__ beta, const int* __restrict__ Tp,
    u16* __restrict__ rate, float* __restrict__ colsum)
{
    // slot = A[128][32] (8KB) + B[128][32] (8KB) = 16KB; 3 slots = 48KB
    __shared__ __align__(16) u16 lds[3 * 8192];

    const int t = threadIdx.x;
    const int l = t & 63, w = t >> 6;          // 8 waves
    const int wm = w >> 1, wn = w & 1;         // 4M x 2N, wave-tile 32x64

    // per-XCD 8bm x 16bn rectangle (grid 32x32 = 1024 blocks)
    const int flat = blockIdx.y * gridDim.x + blockIdx.x;   // 0..1023
    const int xcd = flat & 7, wi = flat >> 3;               // wi 0..127
    const int bm = ((xcd & 3) * 8 + (wi & 7)) * 128;
    const int bn = ((xcd >> 2) * 16 + (wi >> 3)) * 128;

    // staging: issue = 8KB (128 rows x 64B) staged by 512 threads x 16B;
    // dest linear t*16B; source k pre-swizzled (involution w/ read XOR,
    // key = (row>>1)&3 = (t>>3)&3) — R12-proven pattern
    const int koff = (((t & 3) ^ ((t >> 3) & 3)) << 3);
    const int srow = t >> 2;                   // 0..127
    const size_t gA = (size_t)(bm + srow) * DDIM + koff;
    const size_t gB = (size_t)(bn + srow) * DDIM + koff;
    const int dst = t * 8;

#define STG(slot, step) do {                                                  \
    const size_t k0_ = (size_t)(step) << 5;                                   \
    u16* Lb_ = &lds[(slot) * 8192];                                           \
    gload_lds16(xh + gA + k0_, Lb_ + dst);                                    \
    gload_lds16(wh + gB + k0_, Lb_ + 4096 + dst);                             \
} while (0)

    // fragment reads (0-conflict XOR, R12-proven)
    const int lr = l & 15, lk = l >> 4;
    const int psl = ((lk ^ ((lr >> 1) & 3)) << 3);

    f32x4 acc[2][4];
#pragma unroll
    for (int m = 0; m < 2; ++m)
#pragma unroll
        for (int n = 0; n < 4; ++n) acc[m][n] = (f32x4){0.f, 0.f, 0.f, 0.f};

    // prologue: stage tiles 0,1 (4 loads in flight)
    STG(0, 0);
    STG(1, 1);

    const int NT = DDIM / 32;   // 32
#pragma unroll 1
    for (int ts = 0; ts < NT; ++ts) {
        // counted wait: tile ts's 2 loads landed (<=2 newest may pend)
        if (ts + 1 < NT) { asm volatile("s_waitcnt vmcnt(2)" ::: "memory"); }
        else             { asm volatile("s_waitcnt vmcnt(0)" ::: "memory"); }
        __builtin_amdgcn_s_barrier();

        // stage tile ts+2 into the slot last read at ts-1 (race-free)
        if (ts + 2 < NT) STG((ts + 2) % 3, ts + 2);

        const int sb = (ts % 3) * 8192;
        f16x8 a[2], b[4];
#pragma unroll
        for (int m = 0; m < 2; ++m) {
            const int rowin = wm * 32 + m * 16 + lr;   // 0..127
            a[m] = *(const f16x8*)&lds[sb + rowin * 32 + psl];
        }
#pragma unroll
        for (int n = 0; n < 4; ++n) {
            const int rowin = wn * 64 + n * 16 + lr;   // 0..127
            b[n] = *(const f16x8*)&lds[sb + 4096 + rowin * 32 + psl];
        }
        __builtin_amdgcn_s_setprio(1);
#pragma unroll
        for (int m = 0; m < 2; ++m)
#pragma unroll
            for (int n = 0; n < 4; ++n)
                acc[m][n] = MFMA16(a[m], b[n], acc[m][n]);
        __builtin_amdgcn_s_setprio(0);
    }
#undef STG

    // ---- epilogue: LIF recurrence, rate write, fused column sums ----
    const int T = Tp[0];
    const float invT = 1.0f / (float)T;
    const int fbase = bn + wn * 64;
    float betav[4], colacc[4];
#pragma unroll
    for (int n = 0; n < 4; ++n) { betav[n] = beta[fbase + n * 16 + lr]; colacc[n] = 0.f; }

#pragma unroll
    for (int m = 0; m < 2; ++m) {
#pragma unroll
        for (int r = 0; r < 4; ++r) {
            const int row = bm + wm * 32 + m * 16 + lk * 4 + r;
            u16* rp = rate + (size_t)row * FDIM + fbase + lr;
#pragma unroll
            for (int n = 0; n < 4; ++n) {
                const float h = acc[m][n][r];
                const float bet = betav[n];
                float v = 0.f, ss = 0.f;
                if (T == 8) {
#pragma unroll
                    for (int tt = 0; tt < 8; ++tt) {
                        v = fmaf(bet, v, h);
                        float s = (v > 1.0f) ? 1.0f : 0.0f;
                        ss += s; v -= s;
                    }
                } else {
                    for (int tt = 0; tt < T; ++tt) {
                        v = fmaf(bet, v, h);
                        float s = (v > 1.0f) ? 1.0f : 0.0f;
                        ss += s; v -= s;
                    }
                }
                const float rv = ss * invT;                 // exact k/8 (fp16-exact)
                rp[n * 16] = f2h_bits(rv);
                colacc[n] += rv;
            }
        }
    }
#pragma unroll
    for (int n = 0; n < 4; ++n) {
        float ca = colacc[n];
        ca += __shfl_xor(ca, 16, 64);
        ca += __shfl_xor(ca, 32, 64);
        if (lk == 0) atomicAdd(&colsum[fbase + n * 16 + lr], ca);  // exact eighths
    }
}

// ---- down-GEMM: 128x128 tile, BK=64, 8 waves (2Mx4N, wave-tile 64x32),
//      fp16 16x16x32 MFMA, 3-slot counted-vmcnt rotation, 0-conflict XOR LDS.
//      out = rate(fp16) @ wd(fp16)^T, fp32 out. (R8-proven, unchanged) ----
__global__ __launch_bounds__(512, 1) void down_mfma(
    const u16* __restrict__ rate, const u16* __restrict__ wd,
    float* __restrict__ out)
{
    __shared__ __align__(16) u16 lds[3 * 16384];

    const int t = threadIdx.x;
    const int l = t & 63, w = t >> 6;
    const int wm = w >> 2, wn = w & 3;          // wave tile 64x32

    const int flat = blockIdx.y * gridDim.x + blockIdx.x;   // 0..255
    const int xcd = flat & 7, wi = flat >> 3;               // wi 0..31
    const int bm = ((xcd & 3) * 8 + (wi & 7)) * 128;
    const int bn = ((xcd >> 2) * 4 + (wi >> 3)) * 128;

    const int srow = t >> 3;                                // 0..63
    const int koff = (((t & 7) ^ ((t >> 3) & 7)) << 3);
    const size_t gA0 = (size_t)(bm + srow) * FDIM + koff;
    const size_t gA1 = gA0 + (size_t)64 * FDIM;
    const size_t gB0 = (size_t)(bn + srow) * FDIM + koff;
    const size_t gB1 = gB0 + (size_t)64 * FDIM;
    const int dst = t * 8;

#define STD(slot, step) do {                                                  \
    const size_t k0_ = (size_t)(step) << 6;                                   \
    u16* Lb_ = &lds[(slot) * 16384];                                          \
    gload_lds16(rate + gA0 + k0_, Lb_ + dst);                                 \
    gload_lds16(rate + gA1 + k0_, Lb_ + 4096 + dst);                          \
    gload_lds16(wd + gB0 + k0_, Lb_ + 8192 + dst);                            \
    gload_lds16(wd + gB1 + k0_, Lb_ + 12288 + dst);                           \
} while (0)

    const int lr = l & 15, lk = l >> 4;
    const int key = lr & 7;
    const int ps0 = ((0 * 4 + lk) ^ key) << 3;
    const int ps1 = ((1 * 4 + lk) ^ key) << 3;

    f32x4 acc[4][2];
#pragma unroll
    for (int m = 0; m < 4; ++m) {
        acc[m][0] = (f32x4){0.f, 0.f, 0.f, 0.f};
        acc[m][1] = (f32x4){0.f, 0.f, 0.f, 0.f};
    }

    STD(0, 0);
    STD(1, 1);

    const int NT = FDIM / 64;   // 64
#pragma unroll 1
    for (int ts = 0; ts < NT; ++ts) {
        if (ts + 1 < NT) { asm volatile("s_waitcnt vmcnt(4)" ::: "memory"); }
        else             { asm volatile("s_waitcnt vmcnt(0)" ::: "memory"); }
        __builtin_amdgcn_s_barrier();

        if (ts + 2 < NT) STD((ts + 2) % 3, ts + 2);

        const int sb = (ts % 3) * 16384;
        f16x8 a[4][2], b[2][2];
#pragma unroll
        for (int m = 0; m < 4; ++m) {
            const int ro = sb + (wm * 64 + m * 16 + lr) * 64;
            a[m][0] = *(const f16x8*)&lds[ro + ps0];
            a[m][1] = *(const f16x8*)&lds[ro + ps1];
        }
#pragma unroll
        for (int n = 0; n < 2; ++n) {
            const int ro = sb + 8192 + (wn * 32 + n * 16 + lr) * 64;
            b[n][0] = *(const f16x8*)&lds[ro + ps0];
            b[n][1] = *(const f16x8*)&lds[ro + ps1];
        }
        __builtin_amdgcn_s_setprio(1);
#pragma unroll
        for (int m = 0; m < 4; ++m)
#pragma unroll
            for (int n = 0; n < 2; ++n) {
                f32x4 c = acc[m][n];
                c = MFMA16(a[m][0], b[n][0], c);
                c = MFMA16(a[m][1], b[n][1], c);
                acc[m][n] = c;
            }
        __builtin_amdgcn_s_setprio(0);
    }
#undef STD

#pragma unroll
    for (int n = 0; n < 2; ++n) {
        const int d = bn + wn * 32 + n * 16 + lr;
#pragma unroll
        for (int m = 0; m < 4; ++m) {
            const int row0 = bm + wm * 64 + m * 16 + lk * 4;
#pragma unroll
            for (int r = 0; r < 4; ++r)
                out[(size_t)(row0 + r) * DDIM + d] = acc[m][n][r];
        }
    }
}

// ---- rate_per_unit ----
__global__ void finalize_rpu(const float* __restrict__ colsum, float* __restrict__ out_rpu) {
    const int f = blockIdx.x * 256 + threadIdx.x;
    out_rpu[f] = colsum[f] * (1.0f / (float)N_ROWS);
}

extern "C" void kernel_launch(void* const* d_in, const int* in_sizes, int n_in,
                              void* d_out, int out_size, void* d_ws, size_t ws_size,
                              hipStream_t stream) {
    const float* x     = (const float*)d_in[0];
    const float* wup   = (const float*)d_in[1];
    const float* wdown = (const float*)d_in[2];
    const float* beta  = (const float*)d_in[3];
    const int*   Tp    = (const int*)d_in[4];

    float* out     = (float*)d_out;
    float* out_rpu = out + (size_t)N_ROWS * DDIM;

    char* ws = (char*)d_ws;
    u16* rate = (u16*)ws;                                   // 33,554,432 B
    u16* xh   = (u16*)(ws + 33554432);
    u16* wh   = (u16*)(ws + 33554432 + 8388608);
    u16* wd   = (u16*)(ws + 33554432 + 2 * 8388608);
    float* colsum = (float*)(ws + 33554432 + 3 * 8388608);

    split_all<<<2048, 256, 0, stream>>>(x, wup, wdown, xh, wh, wd, colsum);

    up_mfma<<<dim3(32, 32), 512, 0, stream>>>(xh, wh, beta, Tp, rate, colsum);

    finalize_rpu<<<FDIM / 256, 256, 0, stream>>>(colsum, out_rpu);

    down_mfma<<<dim3(DDIM / 128, N_ROWS / 128), 512, 0, stream>>>(rate, wd, out);
}